// Round 1
// baseline (769.806 us; speedup 1.0000x reference)
//
#include <hip/hip_runtime.h>

// MovingAverage: data [B,T,D] fp32 -> (smoothing, residue) both [B,T,D] fp32.
// smoothing[b,t,d] = mean(data[b, max(t-12,0):min(t+12,T), d]); residue = data - smoothing.
// Sliding-window running sum per (b, d4-column), chunked along T.
// Memory-bound: 256 MiB in + 512 MiB out -> ~122 us floor @ 6.3 TB/s.

#define B_ 64
#define T_ 8192
#define D_ 128
#define DQ 32          // D/4 float4 columns per row
#define LW 12
#define RW 12
#define WIN 24
#define TCHUNK 64      // timesteps per subunit; halo overhead 24/64 = 1.375x reads
#define SUBS 8         // (b,chunk) subunits per 256-thread block
#define CHUNKS (T_ / TCHUNK)   // 128

typedef float v4f __attribute__((ext_vector_type(4)));

__global__ __launch_bounds__(256) void ma_kernel(const v4f* __restrict__ in,
                                                 v4f* __restrict__ sm,
                                                 v4f* __restrict__ rs) {
    const int tid  = threadIdx.x;
    const int dq   = tid & 31;        // which float4 column
    const int sub  = tid >> 5;        // subunit 0..7
    const int pair = blockIdx.x * SUBS + sub;   // (b, chunk) flat
    const int chunk = pair & (CHUNKS - 1);      // CHUNKS = 128 (pow2)
    const int b     = pair >> 7;                // pair / 128
    const int t0    = chunk * TCHUNK;

    const size_t base = (size_t)b * T_ * DQ + dq;
    const v4f* __restrict__ col = in + base;
    v4f* __restrict__ smc = sm + base;
    v4f* __restrict__ rsc = rs + base;

    // ---- init running sum over [max(t0-12,0), min(t0+12,T)) ----
    v4f s = {0.f, 0.f, 0.f, 0.f};
    int lo = t0 - LW; if (lo < 0) lo = 0;
    int hi = t0 + RW; if (hi > T_) hi = T_;
    for (int u = lo; u < hi; ++u) {
        s += col[u * DQ];
    }

    if (t0 >= LW && t0 + TCHUNK + RW <= T_) {
        // ---- fast path: no clamping anywhere in this chunk, window == 24 ----
        const float inv = 1.0f / 24.0f;
        #pragma unroll 4
        for (int i = 0; i < TCHUNK; ++i) {
            const int t = t0 + i;
            const int off = t * DQ;
            v4f c = col[off];
            v4f a = col[off + RW * DQ];   // data[t+12]
            v4f d = col[off - LW * DQ];   // data[t-12]
            v4f m = s * inv;
            v4f r = c - m;
            __builtin_nontemporal_store(m, smc + off);
            __builtin_nontemporal_store(r, rsc + off);
            s += a - d;
        }
    } else {
        // ---- general path: boundary chunks (chunk 0 and last) ----
        for (int i = 0; i < TCHUNK; ++i) {
            const int t = t0 + i;
            int l = t - LW; if (l < 0) l = 0;
            int r_ = t + RW; if (r_ > T_) r_ = T_;
            const float inv = (r_ - l == WIN) ? (1.0f / 24.0f)
                                              : (1.0f / (float)(r_ - l));
            const int off = t * DQ;
            v4f c = col[off];
            v4f m = s * inv;
            v4f r = c - m;
            __builtin_nontemporal_store(m, smc + off);
            __builtin_nontemporal_store(r, rsc + off);
            if (t + RW < T_) s += col[off + RW * DQ];
            if (t >= LW)     s -= col[off - LW * DQ];
        }
    }
}

extern "C" void kernel_launch(void* const* d_in, const int* in_sizes, int n_in,
                              void* d_out, int out_size, void* d_ws, size_t ws_size,
                              hipStream_t stream) {
    const v4f* data = (const v4f*)d_in[0];
    v4f* sm = (v4f*)d_out;                               // smoothing first
    v4f* rs = sm + (size_t)B_ * T_ * DQ;                 // then residue
    const int n_pairs = B_ * CHUNKS;                     // 8192
    dim3 grid(n_pairs / SUBS);                           // 1024 blocks
    ma_kernel<<<grid, 256, 0, stream>>>(data, sm, rs);
}